// Round 2
// baseline (927.361 us; speedup 1.0000x reference)
//
#include <hip/hip_runtime.h>

typedef unsigned short u16;
typedef unsigned int u32;
typedef __attribute__((ext_vector_type(8))) short s16x8;
typedef __attribute__((ext_vector_type(8))) u16 u16x8;
typedef __attribute__((ext_vector_type(4))) float f32x4;
typedef __attribute__((ext_vector_type(4))) u32 u32x4;

#define SEQ 2048
#define NH 32
#define NKV 8

__device__ __forceinline__ u16 f2bf(float f) {
  union { float f; u32 u; } v; v.f = f;
  u32 r = v.u + 0x7FFFu + ((v.u >> 16) & 1u);
  return (u16)(r >> 16);
}
__device__ __forceinline__ float bf2f(u16 u) {
  union { u32 u; float f; } v; v.u = ((u32)u) << 16;
  return v.f;
}
__device__ __forceinline__ void gll16(u16* lds, const u16* g) {
  __builtin_amdgcn_global_load_lds(
      (const __attribute__((address_space(1))) u32*)g,
      (__attribute__((address_space(3))) u32*)lds, 16, 0, 0);
}

// ---------------- fp32 -> bf16 cast (x) ----------------
__global__ void k_conv_bf16(const float* __restrict__ in, u16* __restrict__ out) {
  long i = ((long)blockIdx.x * 256 + threadIdx.x) * 4;
  const float4 v = *(const float4*)&in[i];
  ushort4 ov = { f2bf(v.x), f2bf(v.y), f2bf(v.z), f2bf(v.w) };
  *(ushort4*)&out[i] = ov;
}

// ------------- W (K x N fp32) -> Wt (N x K bf16) -------------
__global__ void k_transpose_bf16(const float* __restrict__ W, u16* __restrict__ Wt,
                                 int K, int N) {
  __shared__ u16 T[64 * 65];
  int n0 = blockIdx.x * 64, k0 = blockIdx.y * 64;
  int t = threadIdx.x;
  int cr = t >> 4, cc = (t & 15) * 4;
#pragma unroll
  for (int r2 = 0; r2 < 4; ++r2) {
    int k = cr + r2 * 16;
    const float4 v = *(const float4*)&W[(long)(k0 + k) * N + n0 + cc];
    u16* d = &T[k * 65 + cc];
    d[0] = f2bf(v.x); d[1] = f2bf(v.y); d[2] = f2bf(v.z); d[3] = f2bf(v.w);
  }
  __syncthreads();
#pragma unroll
  for (int r2 = 0; r2 < 4; ++r2) {
    int n = cr + r2 * 16;
    ushort4 ov = { T[(cc + 0) * 65 + n], T[(cc + 1) * 65 + n],
                   T[(cc + 2) * 65 + n], T[(cc + 3) * 65 + n] };
    *(ushort4*)&Wt[(long)(n0 + n) * K + k0 + cc] = ov;
  }
}

// ---------------- RoPE tables (S x 64, fp32) ----------------
__global__ void k_rope_table(float* __restrict__ cosT, float* __restrict__ sinT) {
  int id = blockIdx.x * 256 + threadIdx.x;  // S*64
  int s = id >> 6, i = id & 63;
  float inv = powf(10000.0f, -(float)i * (1.0f / 64.0f));
  float f = (float)s * inv;
  float sv, cv;
  sincosf(f, &sv, &cv);
  cosT[id] = cv; sinT[id] = sv;
}

// ------------- RoPE in-place on Q (131072 rows) + K (32768 rows) -------------
__global__ void k_rope_apply(u16* __restrict__ Qb, u16* __restrict__ Kb,
                             const float* __restrict__ cosT, const float* __restrict__ sinT) {
  int id = blockIdx.x * 256 + threadIdx.x;  // 163840*64
  int i = id & 63;
  int row = id >> 6;
  u16* base = (row < 131072) ? (Qb + (long)row * 128) : (Kb + (long)(row - 131072) * 128);
  int s = row & (SEQ - 1);
  float c = cosT[s * 64 + i], sn = sinT[s * 64 + i];
  float x0 = bf2f(base[i]), x1 = bf2f(base[i + 64]);
  base[i] = f2bf(x0 * c - x1 * sn);
  base[i + 64] = f2bf(x1 * c + x0 * sn);
}

// ------------- m97-style bf16 GEMM: A(MxK) @ Bt(NxK)^T -------------
// MODE 0: QKV epilogue (scatter bf16 into (b,h,s,d) Q/K/V).  MODE 1: fp32 out + bias.
template <int MODE>
__global__ __launch_bounds__(256, 2) void k_gemm_bt(
    const u16* __restrict__ A, const u16* __restrict__ Bt,
    float* __restrict__ Cf, const float* __restrict__ bias,
    u16* __restrict__ Qb, u16* __restrict__ Kb, u16* __restrict__ Vb,
    int K, int nbn) {
  __shared__ u16 As[128 * 32];
  __shared__ u16 Bs[128 * 32];
  int bid = blockIdx.x;
  int cpx = (int)gridDim.x >> 3;                 // grid % 8 == 0 by construction
  int swz = (bid & 7) * cpx + (bid >> 3);        // XCD-contiguous logical ids
  int bm = swz / nbn, bn = swz - bm * nbn;
  int tid = threadIdx.x;
  int lane = tid & 63, wave = tid >> 6;
  int lo = lane & 15, hi = lane >> 4;
  int wm = (wave >> 1) * 64, wn = (wave & 1) * 64;
  f32x4 zero4 = {0.f, 0.f, 0.f, 0.f};
  f32x4 acc[4][4];
#pragma unroll
  for (int m = 0; m < 4; ++m)
#pragma unroll
    for (int n = 0; n < 4; ++n) acc[m][n] = zero4;
  const u16* Ab = A + (long)bm * 128 * K;
  const u16* Bb = Bt + (long)bn * 128 * K;
  for (int kt = 0; kt < K; kt += 32) {
#pragma unroll
    for (int j = 0; j < 2; ++j) {
      int e = (j * 256 + tid) * 8;          // bf16 element index in 128x32 tile
      int row = e >> 5, col = e & 31;
      gll16(&As[e], &Ab[(long)row * K + kt + col]);
      gll16(&Bs[e], &Bb[(long)row * K + kt + col]);
    }
    __syncthreads();
    s16x8 af[4], bf[4];
#pragma unroll
    for (int m = 0; m < 4; ++m) af[m] = *(const s16x8*)&As[(wm + m * 16 + lo) * 32 + hi * 8];
#pragma unroll
    for (int n = 0; n < 4; ++n) bf[n] = *(const s16x8*)&Bs[(wn + n * 16 + lo) * 32 + hi * 8];
#pragma unroll
    for (int m = 0; m < 4; ++m)
#pragma unroll
      for (int n = 0; n < 4; ++n)
        acc[m][n] = __builtin_amdgcn_mfma_f32_16x16x32_bf16(af[m], bf[n], acc[m][n], 0, 0, 0);
    __syncthreads();
  }
#pragma unroll
  for (int m = 0; m < 4; ++m) {
#pragma unroll
    for (int n = 0; n < 4; ++n) {
      int colg = bn * 128 + wn + n * 16 + lo;
#pragma unroll
      for (int r = 0; r < 4; ++r) {
        int rowg = bm * 128 + wm + m * 16 + hi * 4 + r;
        float v = acc[m][n][r];
        if (MODE == 1) {
          Cf[(long)rowg * 4096 + colg] = v + bias[colg];
        } else {
          int bb = rowg >> 11, s = rowg & 2047;
          u16 u = f2bf(v);
          int d = colg & 127;
          if (colg < 4096) {
            int hh = colg >> 7;
            Qb[(((long)bb * NH + hh) * SEQ + s) * 128 + d] = u;
          } else if (colg < 5120) {
            int hh = (colg - 4096) >> 7;
            Kb[(((long)bb * NKV + hh) * SEQ + s) * 128 + d] = u;
          } else {
            int hh = (colg - 5120) >> 7;
            Vb[(((long)bb * NKV + hh) * SEQ + s) * 128 + d] = u;
          }
        }
      }
    }
  }
}

// ------------- causal GQA flash attention, 4 waves x 16 q-rows, KVBLK=32 -------------
__global__ __launch_bounds__(256, 2) void k_attn(
    const u16* __restrict__ Qb, const u16* __restrict__ Kb, const u16* __restrict__ Vb,
    u16* __restrict__ AO) {
  __shared__ u16 Ks[32 * 128];   // row-major, XOR-swizzled ((row&7)<<4)
  __shared__ u16 Vs[128 * 32];   // transposed [d][key], swizzled (((d>>1)&3)<<4)
  __shared__ u16 Ps[4][512];     // per-wave P bounce, swizzled (((row>>1)&3)<<4)
  int qt = blockIdx.x, bh = blockIdx.y;
  int b = bh >> 5, h = bh & 31, kvh = h >> 2;
  int tid = threadIdx.x, lane = tid & 63, wave = tid >> 6;
  int lo = lane & 15, hi = lane >> 4;
  int qb0 = qt * 64, q0 = qb0 + wave * 16;

  const u16* Qrow = Qb + ((long)(b * NH + h) * SEQ + q0 + lo) * 128;
  s16x8 qf[4];
#pragma unroll
  for (int kb = 0; kb < 4; ++kb) qf[kb] = *(const s16x8*)&Qrow[kb * 32 + hi * 8];

  const u16* Kbase = Kb + (long)(b * NKV + kvh) * SEQ * 128;
  const u16* Vbase = Vb + (long)(b * NKV + kvh) * SEQ * 128;

  f32x4 zero4 = {0.f, 0.f, 0.f, 0.f};
  f32x4 o[8];
#pragma unroll
  for (int i = 0; i < 8; ++i) o[i] = zero4;
  float m_run[4] = {-1e30f, -1e30f, -1e30f, -1e30f};
  float l_run[4] = {0.f, 0.f, 0.f, 0.f};

  char* KsB = (char*)Ks;
  char* VsB = (char*)Vs;
  char* PsB = (char*)(&Ps[wave][0]);
  const float scale = 0.088388347648318447f;  // 1/sqrt(128)

  int ktiles = (qb0 + 64) >> 5;
  for (int t = 0; t < ktiles; ++t) {
    int kt = t << 5;
    {  // stage K (32x128 bf16)
      int row = tid >> 3, ch = tid & 7;
      const u16* src = Kbase + (long)(kt + row) * 128 + ch * 16;
      u32x4 v0 = *(const u32x4*)src;
      u32x4 v1 = *(const u32x4*)(src + 8);
      int b0 = row * 256 + ch * 32, sw = (row & 7) << 4;
      *(u32x4*)(KsB + (b0 ^ sw)) = v0;
      *(u32x4*)(KsB + ((b0 + 16) ^ sw)) = v1;
    }
    {  // stage V transposed -> Vs[d][key]
      int key = tid & 31, d0 = (tid >> 5) * 16;
      const u16* src = Vbase + (long)(kt + key) * 128 + d0;
      u16x8 w0 = *(const u16x8*)src;
      u16x8 w1 = *(const u16x8*)(src + 8);
#pragma unroll
      for (int j = 0; j < 8; ++j) {
        int d = d0 + j;
        *(u16*)(VsB + ((d * 64 + key * 2) ^ (((d >> 1) & 3) << 4))) = w0[j];
      }
#pragma unroll
      for (int j = 0; j < 8; ++j) {
        int d = d0 + 8 + j;
        *(u16*)(VsB + ((d * 64 + key * 2) ^ (((d >> 1) & 3) << 4))) = w1[j];
      }
    }
    __syncthreads();
    if (kt <= q0 + 15) {  // tile relevant for this wave's rows
      f32x4 s0 = zero4, s1 = zero4;
#pragma unroll
      for (int kb = 0; kb < 4; ++kb) {
        int key0 = lo, key1 = 16 + lo;
        s16x8 kf0 = *(const s16x8*)(KsB + ((key0 * 256 + kb * 64 + hi * 16) ^ ((key0 & 7) << 4)));
        s16x8 kf1 = *(const s16x8*)(KsB + ((key1 * 256 + kb * 64 + hi * 16) ^ ((key1 & 7) << 4)));
        s0 = __builtin_amdgcn_mfma_f32_16x16x32_bf16(qf[kb], kf0, s0, 0, 0, 0);
        s1 = __builtin_amdgcn_mfma_f32_16x16x32_bf16(qf[kb], kf1, s1, 0, 0, 0);
      }
      bool need_mask = (kt + 31) > q0;
#pragma unroll
      for (int r = 0; r < 4; ++r) {
        float a0 = s0[r] * scale, a1 = s1[r] * scale;
        if (need_mask) {
          int rr = q0 + hi * 4 + r;
          if (kt + lo > rr) a0 = -1e30f;
          if (kt + 16 + lo > rr) a1 = -1e30f;
        }
        float vm = fmaxf(a0, a1);
        vm = fmaxf(vm, __shfl_xor(vm, 1));
        vm = fmaxf(vm, __shfl_xor(vm, 2));
        vm = fmaxf(vm, __shfl_xor(vm, 4));
        vm = fmaxf(vm, __shfl_xor(vm, 8));
        float mn = fmaxf(m_run[r], vm);
        float corr = __expf(m_run[r] - mn);
        m_run[r] = mn;
        float p0 = __expf(a0 - mn), p1 = __expf(a1 - mn);
        float rs = p0 + p1;
        rs += __shfl_xor(rs, 1); rs += __shfl_xor(rs, 2);
        rs += __shfl_xor(rs, 4); rs += __shfl_xor(rs, 8);
        l_run[r] = l_run[r] * corr + rs;
#pragma unroll
        for (int dt = 0; dt < 8; ++dt) o[dt][r] *= corr;
        int prow = hi * 4 + r, sw = ((prow >> 1) & 3) << 4;
        *(u16*)(PsB + ((prow * 64 + lo * 2) ^ sw)) = f2bf(p0);
        *(u16*)(PsB + ((prow * 64 + 32 + lo * 2) ^ sw)) = f2bf(p1);
      }
      asm volatile("s_waitcnt lgkmcnt(0)" ::: "memory");
      __builtin_amdgcn_sched_barrier(0);
      s16x8 pf = *(const s16x8*)(PsB + ((lo * 64 + hi * 16) ^ (((lo >> 1) & 3) << 4)));
#pragma unroll
      for (int dt = 0; dt < 8; ++dt) {
        int d = dt * 16 + lo;
        s16x8 vf = *(const s16x8*)(VsB + ((d * 64 + hi * 16) ^ (((d >> 1) & 3) << 4)));
        o[dt] = __builtin_amdgcn_mfma_f32_16x16x32_bf16(pf, vf, o[dt], 0, 0, 0);
      }
    }
    __syncthreads();
  }
#pragma unroll
  for (int dt = 0; dt < 8; ++dt) {
#pragma unroll
    for (int r = 0; r < 4; ++r) {
      int s = q0 + hi * 4 + r;
      AO[((long)(b * SEQ + s)) * 4096 + h * 128 + dt * 16 + lo] = f2bf(o[dt][r] / l_run[r]);
    }
  }
}

extern "C" void kernel_launch(void* const* d_in, const int* in_sizes, int n_in,
                              void* d_out, int out_size, void* d_ws, size_t ws_size,
                              hipStream_t stream) {
  const float* x  = (const float*)d_in[0];
  const float* Wq = (const float*)d_in[1];
  const float* Wk = (const float*)d_in[2];
  const float* Wv = (const float*)d_in[3];
  const float* Wo = (const float*)d_in[4];
  const float* bo = (const float*)d_in[5];
  float* out = (float*)d_out;

  char* ws = (char*)d_ws;
  u16* xb     = (u16*)(ws);               // 33554432 B; reused as AO after gemm1
  u16* Wt     = (u16*)(ws + 33554432);    // 50331648 B (QKV cat); reused for Wo^T
  u16* Qb     = (u16*)(ws + 83886080);    // 33554432 B
  u16* Kb     = (u16*)(ws + 117440512);   // 8388608 B
  u16* Vb     = (u16*)(ws + 125829120);   // 8388608 B
  float* cosT = (float*)(ws + 134217728); // 524288 B
  float* sinT = (float*)(ws + 134742016); // 524288 B
  if (ws_size < 135266304) return;        // need 129 MiB scratch
  u16* AO  = xb;
  u16* Wto = Wt;

  k_conv_bf16<<<16384, 256, 0, stream>>>(x, xb);
  k_transpose_bf16<<<dim3(64, 64), 256, 0, stream>>>(Wq, Wt, 4096, 4096);
  k_transpose_bf16<<<dim3(16, 64), 256, 0, stream>>>(Wk, Wt + (long)4096 * 4096, 4096, 1024);
  k_transpose_bf16<<<dim3(16, 64), 256, 0, stream>>>(Wv, Wt + (long)5120 * 4096, 4096, 1024);
  k_rope_table<<<512, 256, 0, stream>>>(cosT, sinT);
  k_gemm_bt<0><<<1536, 256, 0, stream>>>(xb, Wt, nullptr, nullptr, Qb, Kb, Vb, 4096, 48);
  k_rope_apply<<<40960, 256, 0, stream>>>(Qb, Kb, cosT, sinT);
  k_transpose_bf16<<<dim3(64, 64), 256, 0, stream>>>(Wo, Wto, 4096, 4096);
  k_attn<<<dim3(32, 64), 256, 0, stream>>>(Qb, Kb, Vb, AO);
  k_gemm_bt<1><<<1024, 256, 0, stream>>>(AO, Wto, out, bo, nullptr, nullptr, nullptr, 4096, 32);
}

// Round 4
// 684.748 us; speedup vs baseline: 1.3543x; 1.3543x over previous
//
#include <hip/hip_runtime.h>

typedef unsigned short u16;
typedef unsigned int u32;
typedef __attribute__((ext_vector_type(8))) short s16x8;
typedef __attribute__((ext_vector_type(8))) u16 u16x8;
typedef __attribute__((ext_vector_type(4))) float f32x4;
typedef __attribute__((ext_vector_type(4))) u32 u32x4;

#define SEQ 2048
#define NH 32
#define NKV 8

__device__ __forceinline__ u16 f2bf(float f) {
  union { float f; u32 u; } v; v.f = f;
  u32 r = v.u + 0x7FFFu + ((v.u >> 16) & 1u);
  return (u16)(r >> 16);
}
__device__ __forceinline__ float bf2f(u16 u) {
  union { u32 u; float f; } v; v.u = ((u32)u) << 16;
  return v.f;
}
__device__ __forceinline__ u32 pack2(float a, float b) {
  return (u32)f2bf(a) | ((u32)f2bf(b) << 16);
}
__device__ __forceinline__ void gll16(u16* lds, const u16* g) {
  __builtin_amdgcn_global_load_lds(
      (const __attribute__((address_space(1))) u32*)g,
      (__attribute__((address_space(3))) u32*)lds, 16, 0, 0);
}

// ---------------- fp32 -> bf16 cast (x) ----------------
__global__ void k_conv_bf16(const float* __restrict__ in, u16* __restrict__ out) {
  long i = ((long)blockIdx.x * 256 + threadIdx.x) * 4;
  const float4 v = *(const float4*)&in[i];
  ushort4 ov = { f2bf(v.x), f2bf(v.y), f2bf(v.z), f2bf(v.w) };
  *(ushort4*)&out[i] = ov;
}

// ------------- W (K x N fp32) -> Wt (N x K bf16) -------------
__global__ void k_transpose_bf16(const float* __restrict__ W, u16* __restrict__ Wt,
                                 int K, int N) {
  __shared__ u16 T[64 * 65];
  int n0 = blockIdx.x * 64, k0 = blockIdx.y * 64;
  int t = threadIdx.x;
  int cr = t >> 4, cc = (t & 15) * 4;
#pragma unroll
  for (int r2 = 0; r2 < 4; ++r2) {
    int k = cr + r2 * 16;
    const float4 v = *(const float4*)&W[(long)(k0 + k) * N + n0 + cc];
    u16* d = &T[k * 65 + cc];
    d[0] = f2bf(v.x); d[1] = f2bf(v.y); d[2] = f2bf(v.z); d[3] = f2bf(v.w);
  }
  __syncthreads();
#pragma unroll
  for (int r2 = 0; r2 < 4; ++r2) {
    int n = cr + r2 * 16;
    ushort4 ov = { T[(cc + 0) * 65 + n], T[(cc + 1) * 65 + n],
                   T[(cc + 2) * 65 + n], T[(cc + 3) * 65 + n] };
    *(ushort4*)&Wt[(long)(n0 + n) * K + k0 + cc] = ov;
  }
}

// ------------- V (per head: S x 128 bf16) -> Vt (128 x S bf16) -------------
__global__ void k_vt(const u16* __restrict__ Vb, u16* __restrict__ Vt) {
  __shared__ u16 T[64][136];
  int s0 = blockIdx.x * 64;
  int g = blockIdx.y;  // b*NKV + kv
  const u16* src = Vb + (long)g * SEQ * 128;
  u16* dst = Vt + (long)g * 128 * SEQ;
  int t = threadIdx.x;
#pragma unroll
  for (int i = 0; i < 4; ++i) {
    int c = i * 256 + t;
    int row = c >> 4, col8 = (c & 15) * 8;
    u16x8 v = *(const u16x8*)&src[(long)(s0 + row) * 128 + col8];
#pragma unroll
    for (int j = 0; j < 8; ++j) T[row][col8 + j] = v[j];
  }
  __syncthreads();
#pragma unroll
  for (int i = 0; i < 4; ++i) {
    int c = i * 256 + t;
    int d = c >> 3, k8 = (c & 7) * 8;
    u16x8 v;
#pragma unroll
    for (int j = 0; j < 8; ++j) v[j] = T[k8 + j][d];
    *(u16x8*)&dst[(long)d * SEQ + s0 + k8] = v;
  }
}

// ---------------- RoPE tables (S x 64, fp32) ----------------
__global__ void k_rope_table(float* __restrict__ cosT, float* __restrict__ sinT) {
  int id = blockIdx.x * 256 + threadIdx.x;  // S*64
  int s = id >> 6, i = id & 63;
  float inv = powf(10000.0f, -(float)i * (1.0f / 64.0f));
  float f = (float)s * inv;
  float sv, cv;
  sincosf(f, &sv, &cv);
  cosT[id] = cv; sinT[id] = sv;
}

// ------------- RoPE in-place on Q (131072 rows) + K (32768 rows) -------------
__global__ void k_rope_apply(u16* __restrict__ Qb, u16* __restrict__ Kb,
                             const float* __restrict__ cosT, const float* __restrict__ sinT) {
  int id = blockIdx.x * 256 + threadIdx.x;  // 163840*64
  int i = id & 63;
  int row = id >> 6;
  u16* base = (row < 131072) ? (Qb + (long)row * 128) : (Kb + (long)(row - 131072) * 128);
  int s = row & (SEQ - 1);
  float c = cosT[s * 64 + i], sn = sinT[s * 64 + i];
  float x0 = bf2f(base[i]), x1 = bf2f(base[i + 64]);
  base[i] = f2bf(x0 * c - x1 * sn);
  base[i + 64] = f2bf(x1 * c + x0 * sn);
}

// ------------- m97-style bf16 GEMM: A(MxK) @ Bt(NxK)^T -------------
template <int MODE>
__global__ __launch_bounds__(256, 2) void k_gemm_bt(
    const u16* __restrict__ A, const u16* __restrict__ Bt,
    float* __restrict__ Cf, const float* __restrict__ bias,
    u16* __restrict__ Qb, u16* __restrict__ Kb, u16* __restrict__ Vb,
    int K, int nbn) {
  __shared__ u16 As[128 * 32];
  __shared__ u16 Bs[128 * 32];
  int bid = blockIdx.x;
  int cpx = (int)gridDim.x >> 3;
  int swz = (bid & 7) * cpx + (bid >> 3);
  int bm = swz / nbn, bn = swz - bm * nbn;
  int tid = threadIdx.x;
  int lane = tid & 63, wave = tid >> 6;
  int lo = lane & 15, hi = lane >> 4;
  int wm = (wave >> 1) * 64, wn = (wave & 1) * 64;
  f32x4 zero4 = {0.f, 0.f, 0.f, 0.f};
  f32x4 acc[4][4];
#pragma unroll
  for (int m = 0; m < 4; ++m)
#pragma unroll
    for (int n = 0; n < 4; ++n) acc[m][n] = zero4;
  const u16* Ab = A + (long)bm * 128 * K;
  const u16* Bb = Bt + (long)bn * 128 * K;
  for (int kt = 0; kt < K; kt += 32) {
#pragma unroll
    for (int j = 0; j < 2; ++j) {
      int e = (j * 256 + tid) * 8;
      int row = e >> 5, col = e & 31;
      gll16(&As[e], &Ab[(long)row * K + kt + col]);
      gll16(&Bs[e], &Bb[(long)row * K + kt + col]);
    }
    __syncthreads();
    s16x8 af[4], bf[4];
#pragma unroll
    for (int m = 0; m < 4; ++m) af[m] = *(const s16x8*)&As[(wm + m * 16 + lo) * 32 + hi * 8];
#pragma unroll
    for (int n = 0; n < 4; ++n) bf[n] = *(const s16x8*)&Bs[(wn + n * 16 + lo) * 32 + hi * 8];
#pragma unroll
    for (int m = 0; m < 4; ++m)
#pragma unroll
      for (int n = 0; n < 4; ++n)
        acc[m][n] = __builtin_amdgcn_mfma_f32_16x16x32_bf16(af[m], bf[n], acc[m][n], 0, 0, 0);
    __syncthreads();
  }
#pragma unroll
  for (int m = 0; m < 4; ++m) {
#pragma unroll
    for (int n = 0; n < 4; ++n) {
      int colg = bn * 128 + wn + n * 16 + lo;
#pragma unroll
      for (int r = 0; r < 4; ++r) {
        int rowg = bm * 128 + wm + m * 16 + hi * 4 + r;
        float v = acc[m][n][r];
        if (MODE == 1) {
          Cf[(long)rowg * 4096 + colg] = v + bias[colg];
        } else {
          int bb = rowg >> 11, s = rowg & 2047;
          u16 u = f2bf(v);
          int d = colg & 127;
          if (colg < 4096) {
            int hh = colg >> 7;
            Qb[(((long)bb * NH + hh) * SEQ + s) * 128 + d] = u;
          } else if (colg < 5120) {
            int hh = (colg - 4096) >> 7;
            Kb[(((long)bb * NKV + hh) * SEQ + s) * 128 + d] = u;
          } else {
            int hh = (colg - 5120) >> 7;
            Vb[(((long)bb * NKV + hh) * SEQ + s) * 128 + d] = u;
          }
        }
      }
    }
  }
}

// ------- K/V^T staging: global->reg (issue early), reg->swizzled LDS (write late) -------
__device__ __forceinline__ void stage_load(u32x4* kr_, u32x4* vr_,
    const u16* __restrict__ Kg, const u16* __restrict__ Vg, int kt, int tid) {
#pragma unroll
  for (int i = 0; i < 4; ++i) {
    int idx = i * 256 + tid;
    int kr = idx >> 4, kc = idx & 15;
    kr_[i] = *(const u32x4*)&Kg[(long)(kt + kr) * 128 + kc * 8];
    int vr = idx >> 3, vc = idx & 7;
    vr_[i] = *(const u32x4*)&Vg[(long)vr * SEQ + kt + vc * 8];
  }
}
__device__ __forceinline__ void stage_write(const u32x4* kr_, const u32x4* vr_,
    u16* Ks, u16* Vs, int tid) {
  char* KsB = (char*)Ks; char* VsB = (char*)Vs;
#pragma unroll
  for (int i = 0; i < 4; ++i) {
    int idx = i * 256 + tid;
    int kr = idx >> 4, kc = idx & 15;
    *(u32x4*)(KsB + ((kr * 256 + kc * 16) ^ ((kr & 7) << 4))) = kr_[i];
    int vr = idx >> 3, vc = idx & 7;
    *(u32x4*)(VsB + ((vr * 128 + vc * 16) ^ ((vr & 7) << 4))) = vr_[i];
  }
}

// ------- causal GQA flash attn: 4 waves x 32 q-rows, KVBLK=64, swapped-operand -------
// QK^T swapped (A=K, B=Q): lane holds S[q=lo][key=a*16+hi*4+r]; softmax in-register.
// PV swapped (A=V^T, B=P^T): P^T B-frag via per-wave swizzled LDS bounce.
__global__ __launch_bounds__(256, 2) void k_attn(
    const u16* __restrict__ Qb, const u16* __restrict__ Kb,
    const u16* __restrict__ Vt, u16* __restrict__ AO) {
  __shared__ u16 Ks0[64 * 128], Ks1[64 * 128], Vs0[128 * 64], Vs1[128 * 64];
  __shared__ u16 Ps[4][2][16][32];  // [wave][qs][q=lo][key_local], 8B-chunk swizzled
  int gid = blockIdx.x;                      // 1024 blocks
  int wid = (gid & 7) * 128 + (gid >> 3);    // XCD-contiguous work ids
  int g = wid >> 6, w = wid & 63;
  int b = g >> 3, kvh = g & 7;
  int h = kvh * 4 + (w >> 4);
  int qt = 15 - (w & 15);                    // long blocks first
  int qb0 = qt * 128;
  int tid = threadIdx.x, lane = tid & 63, wave = tid >> 6;
  int lo = lane & 15, hi = lane >> 4;
  int q0w = qb0 + wave * 32;

  const u16* Kg = Kb + (long)(b * NKV + kvh) * SEQ * 128;
  const u16* Vg = Vt + (long)(b * NKV + kvh) * 128 * SEQ;
  const u16* Qg = Qb + (long)(b * NH + h) * SEQ * 128;

  // Q hoisted: B-frag of swapped QK^T = Q[q=lo][d=ds*32+hi*8+j]
  s16x8 qf[2][4];
#pragma unroll
  for (int qs = 0; qs < 2; ++qs)
#pragma unroll
    for (int ds = 0; ds < 4; ++ds)
      qf[qs][ds] = *(const s16x8*)&Qg[(long)(q0w + qs * 16 + lo) * 128 + ds * 32 + hi * 8];

  f32x4 zero4 = {0.f, 0.f, 0.f, 0.f};
  f32x4 o[2][8];
#pragma unroll
  for (int qs = 0; qs < 2; ++qs)
#pragma unroll
    for (int dt = 0; dt < 8; ++dt) o[qs][dt] = zero4;
  float m_run[2] = {-1e30f, -1e30f};
  float l_run[2] = {0.f, 0.f};
  const float scale = 0.088388347648318447f;  // 1/sqrt(128)

  char* PsQ0 = (char*)&Ps[wave][0][0][0];
  char* PsQ1 = (char*)&Ps[wave][1][0][0];
  int pbase = lo << 6;  // row stride 64B in the bounce buffer

  u32x4 kreg[4], vreg[4];
  int ntiles = (qb0 >> 6) + 2;
  stage_load(kreg, vreg, Kg, Vg, 0, tid);
  stage_write(kreg, vreg, Ks0, Vs0, tid);
  __syncthreads();

  for (int t = 0; t < ntiles; ++t) {
    int kt = t << 6;
    u16* Ks = (t & 1) ? Ks1 : Ks0;
    u16* Vs = (t & 1) ? Vs1 : Vs0;
    bool more = (t + 1 < ntiles);
    if (more) stage_load(kreg, vreg, Kg, Vg, (t + 1) << 6, tid);  // issue early (T14)
    if (kt <= q0w + 31) {
      // ---- QK^T (swapped): lane holds S[q=lo][key=kt+a*16+hi*4+r]
      f32x4 sa[2][4];
#pragma unroll
      for (int qs = 0; qs < 2; ++qs)
#pragma unroll
        for (int a = 0; a < 4; ++a) sa[qs][a] = zero4;
#pragma unroll
      for (int ds = 0; ds < 4; ++ds) {
        s16x8 kf[4];
#pragma unroll
        for (int a = 0; a < 4; ++a)
          kf[a] = *(const s16x8*)&Ks[((a * 16 + lo) << 7) + (((ds * 4 + hi) ^ (lo & 7)) << 3)];
#pragma unroll
        for (int qs = 0; qs < 2; ++qs)
#pragma unroll
          for (int a = 0; a < 4; ++a)
            sa[qs][a] = __builtin_amdgcn_mfma_f32_16x16x32_bf16(kf[a], qf[qs][ds], sa[qs][a], 0, 0, 0);
      }
      bool pmask = (kt + 63) > q0w;
      u32 pp[2][4][2];
#pragma unroll
      for (int qs = 0; qs < 2; ++qs) {
        float pv[16];
        int qrow = q0w + qs * 16 + lo;
#pragma unroll
        for (int a = 0; a < 4; ++a)
#pragma unroll
          for (int r = 0; r < 4; ++r) {
            float s = sa[qs][a][r] * scale;
            if (pmask && (kt + a * 16 + hi * 4 + r) > qrow) s = -1e30f;
            pv[a * 4 + r] = s;
          }
        float mx = pv[0];
#pragma unroll
        for (int i = 1; i < 16; ++i) mx = fmaxf(mx, pv[i]);
        mx = fmaxf(mx, __shfl_xor(mx, 16));
        mx = fmaxf(mx, __shfl_xor(mx, 32));
        float mnew = fmaxf(m_run[qs], mx);
        if (!__all(mnew - m_run[qs] <= 8.0f)) {  // defer-max (T13)
          float corr = __expf(m_run[qs] - mnew);
          m_run[qs] = mnew;
          l_run[qs] *= corr;
#pragma unroll
          for (int dt = 0; dt < 8; ++dt)
#pragma unroll
            for (int r = 0; r < 4; ++r) o[qs][dt][r] *= corr;
        }
        float sum = 0.f;
#pragma unroll
        for (int i = 0; i < 16; ++i) { pv[i] = __expf(pv[i] - m_run[qs]); sum += pv[i]; }
        sum += __shfl_xor(sum, 16);
        sum += __shfl_xor(sum, 32);
        l_run[qs] += sum;
#pragma unroll
        for (int a = 0; a < 4; ++a) {
          pp[qs][a][0] = pack2(pv[a * 4 + 0], pv[a * 4 + 1]);
          pp[qs][a][1] = pack2(pv[a * 4 + 2], pv[a * 4 + 3]);
        }
      }
      // ---- PV (swapped): O^T = mfma(V^T, P^T); P^T B-frag via LDS bounce per kb-half
#pragma unroll
      for (int kb = 0; kb < 2; ++kb) {
#pragma unroll
        for (int qs = 0; qs < 2; ++qs) {
          char* Pw = qs ? PsQ1 : PsQ0;
#pragma unroll
          for (int al = 0; al < 2; ++al) {
            uint2 wv; wv.x = pp[qs][kb * 2 + al][0]; wv.y = pp[qs][kb * 2 + al][1];
            *(uint2*)(Pw + pbase + (((al * 4 + hi) ^ (lo & 7)) << 3)) = wv;
          }
        }
        asm volatile("s_waitcnt lgkmcnt(0)" ::: "memory");
        __builtin_amdgcn_sched_barrier(0);
        union { uint2 u2[2]; s16x8 v; } bu0, bu1;
        bu0.u2[0] = *(uint2*)(PsQ0 + pbase + (((hi * 2 + 0) ^ (lo & 7)) << 3));
        bu0.u2[1] = *(uint2*)(PsQ0 + pbase + (((hi * 2 + 1) ^ (lo & 7)) << 3));
        bu1.u2[0] = *(uint2*)(PsQ1 + pbase + (((hi * 2 + 0) ^ (lo & 7)) << 3));
        bu1.u2[1] = *(uint2*)(PsQ1 + pbase + (((hi * 2 + 1) ^ (lo & 7)) << 3));
#pragma unroll
        for (int dt = 0; dt < 8; ++dt) {
          s16x8 vf = *(const s16x8*)((char*)Vs +
              (((dt * 16 + lo) * 128 + (kb * 4 + hi) * 16) ^ ((lo & 7) << 4)));
          o[0][dt] = __builtin_amdgcn_mfma_f32_16x16x32_bf16(vf, bu0.v, o[0][dt], 0, 0, 0);
          o[1][dt] = __builtin_amdgcn_mfma_f32_16x16x32_bf16(vf, bu1.v, o[1][dt], 0, 0, 0);
        }
      }
    }
    if (more) stage_write(kreg, vreg, (t & 1) ? Ks0 : Ks1, (t & 1) ? Vs0 : Vs1, tid);
    __syncthreads();
  }

  // epilogue: lane holds O[q=lo][d=dt*16+hi*4+r]
#pragma unroll
  for (int qs = 0; qs < 2; ++qs) {
    float inv = 1.0f / l_run[qs];
    long base = ((long)(b * SEQ + q0w + qs * 16 + lo)) * 4096 + h * 128;
#pragma unroll
    for (int dt = 0; dt < 8; ++dt) {
      uint2 wv;
      wv.x = pack2(o[qs][dt][0] * inv, o[qs][dt][1] * inv);
      wv.y = pack2(o[qs][dt][2] * inv, o[qs][dt][3] * inv);
      *(uint2*)&AO[base + dt * 16 + hi * 4] = wv;
    }
  }
}

extern "C" void kernel_launch(void* const* d_in, const int* in_sizes, int n_in,
                              void* d_out, int out_size, void* d_ws, size_t ws_size,
                              hipStream_t stream) {
  const float* x  = (const float*)d_in[0];
  const float* Wq = (const float*)d_in[1];
  const float* Wk = (const float*)d_in[2];
  const float* Wv = (const float*)d_in[3];
  const float* Wo = (const float*)d_in[4];
  const float* bo = (const float*)d_in[5];
  float* out = (float*)d_out;

  char* ws = (char*)d_ws;
  u16* xb     = (u16*)(ws);               // 32 MiB; reused as AO after gemm1
  u16* Wt     = (u16*)(ws + 33554432);    // 48 MiB (QKV cat); first 32 MiB reused for Wo^T
  u16* Vtb    = (u16*)(ws + 67108864);    // 8 MiB (V^T per head, d x S) - tail of Wt region
  u16* Qb     = (u16*)(ws + 83886080);    // 32 MiB
  u16* Kb     = (u16*)(ws + 117440512);   // 8 MiB
  u16* Vb     = (u16*)(ws + 125829120);   // 8 MiB
  float* cosT = (float*)(ws + 134217728); // 512 KiB
  float* sinT = (float*)(ws + 134742016); // 512 KiB
  if (ws_size < 135266304) return;        // need 129 MiB scratch
  u16* AO  = xb;
  u16* Wto = Wt;

  k_conv_bf16<<<16384, 256, 0, stream>>>(x, xb);
  k_transpose_bf16<<<dim3(64, 64), 256, 0, stream>>>(Wq, Wt, 4096, 4096);
  k_transpose_bf16<<<dim3(16, 64), 256, 0, stream>>>(Wk, Wt + (long)4096 * 4096, 4096, 1024);
  k_transpose_bf16<<<dim3(16, 64), 256, 0, stream>>>(Wv, Wt + (long)5120 * 4096, 4096, 1024);
  k_rope_table<<<512, 256, 0, stream>>>(cosT, sinT);
  k_gemm_bt<0><<<1536, 256, 0, stream>>>(xb, Wt, nullptr, nullptr, Qb, Kb, Vb, 4096, 48);
  k_vt<<<dim3(32, 16), 256, 0, stream>>>(Vb, Vtb);
  k_rope_apply<<<40960, 256, 0, stream>>>(Qb, Kb, cosT, sinT);
  k_transpose_bf16<<<dim3(64, 64), 256, 0, stream>>>(Wo, Wto, 4096, 4096);
  k_attn<<<1024, 256, 0, stream>>>(Qb, Kb, Vtb, AO);
  k_gemm_bt<1><<<1024, 256, 0, stream>>>(AO, Wto, out, bo, nullptr, nullptr, nullptr, 4096, 32);
}

// Round 5
// 639.750 us; speedup vs baseline: 1.4496x; 1.0703x over previous
//
#include <hip/hip_runtime.h>

typedef unsigned short u16;
typedef unsigned int u32;
typedef __attribute__((ext_vector_type(8))) short s16x8;
typedef __attribute__((ext_vector_type(8))) u16 u16x8;
typedef __attribute__((ext_vector_type(4))) float f32x4;
typedef __attribute__((ext_vector_type(4))) u32 u32x4;

#define SEQ 2048
#define NH 32
#define NKV 8

__device__ __forceinline__ u16 f2bf(float f) {
  union { float f; u32 u; } v; v.f = f;
  u32 r = v.u + 0x7FFFu + ((v.u >> 16) & 1u);
  return (u16)(r >> 16);
}
__device__ __forceinline__ float bf2f(u16 u) {
  union { u32 u; float f; } v; v.u = ((u32)u) << 16;
  return v.f;
}
__device__ __forceinline__ u32 pack2(float a, float b) {
  return (u32)f2bf(a) | ((u32)f2bf(b) << 16);
}
__device__ __forceinline__ void gll16(u16* lds, const u16* g) {
  __builtin_amdgcn_global_load_lds(
      (const __attribute__((address_space(1))) u32*)g,
      (__attribute__((address_space(3))) u32*)lds, 16, 0, 0);
}

// ---------------- fp32 -> bf16 cast (x) ----------------
__global__ void k_conv_bf16(const float* __restrict__ in, u16* __restrict__ out) {
  long i = ((long)blockIdx.x * 256 + threadIdx.x) * 4;
  const float4 v = *(const float4*)&in[i];
  ushort4 ov = { f2bf(v.x), f2bf(v.y), f2bf(v.z), f2bf(v.w) };
  *(ushort4*)&out[i] = ov;
}

// ------------- W (K x N fp32) -> Wt (N x K bf16) -------------
__global__ void k_transpose_bf16(const float* __restrict__ W, u16* __restrict__ Wt,
                                 int K, int N) {
  __shared__ u16 T[64 * 65];
  int n0 = blockIdx.x * 64, k0 = blockIdx.y * 64;
  int t = threadIdx.x;
  int cr = t >> 4, cc = (t & 15) * 4;
#pragma unroll
  for (int r2 = 0; r2 < 4; ++r2) {
    int k = cr + r2 * 16;
    const float4 v = *(const float4*)&W[(long)(k0 + k) * N + n0 + cc];
    u16* d = &T[k * 65 + cc];
    d[0] = f2bf(v.x); d[1] = f2bf(v.y); d[2] = f2bf(v.z); d[3] = f2bf(v.w);
  }
  __syncthreads();
#pragma unroll
  for (int r2 = 0; r2 < 4; ++r2) {
    int n = cr + r2 * 16;
    ushort4 ov = { T[(cc + 0) * 65 + n], T[(cc + 1) * 65 + n],
                   T[(cc + 2) * 65 + n], T[(cc + 3) * 65 + n] };
    *(ushort4*)&Wt[(long)(n0 + n) * K + k0 + cc] = ov;
  }
}

// ------------- V (per head: S x 128 bf16) -> Vt (128 x S bf16) -------------
__global__ void k_vt(const u16* __restrict__ Vb, u16* __restrict__ Vt) {
  __shared__ u16 T[64][136];
  int s0 = blockIdx.x * 64;
  int g = blockIdx.y;  // b*NKV + kv
  const u16* src = Vb + (long)g * SEQ * 128;
  u16* dst = Vt + (long)g * 128 * SEQ;
  int t = threadIdx.x;
#pragma unroll
  for (int i = 0; i < 4; ++i) {
    int c = i * 256 + t;
    int row = c >> 4, col8 = (c & 15) * 8;
    u16x8 v = *(const u16x8*)&src[(long)(s0 + row) * 128 + col8];
#pragma unroll
    for (int j = 0; j < 8; ++j) T[row][col8 + j] = v[j];
  }
  __syncthreads();
#pragma unroll
  for (int i = 0; i < 4; ++i) {
    int c = i * 256 + t;
    int d = c >> 3, k8 = (c & 7) * 8;
    u16x8 v;
#pragma unroll
    for (int j = 0; j < 8; ++j) v[j] = T[k8 + j][d];
    *(u16x8*)&dst[(long)d * SEQ + s0 + k8] = v;
  }
}

// ---------------- RoPE tables (S x 64, fp32) ----------------
__global__ void k_rope_table(float* __restrict__ cosT, float* __restrict__ sinT) {
  int id = blockIdx.x * 256 + threadIdx.x;  // S*64
  int s = id >> 6, i = id & 63;
  float inv = powf(10000.0f, -(float)i * (1.0f / 64.0f));
  float f = (float)s * inv;
  float sv, cv;
  sincosf(f, &sv, &cv);
  cosT[id] = cv; sinT[id] = sv;
}

// ------------- RoPE in-place on Q (131072 rows) + K (32768 rows) -------------
__global__ void k_rope_apply(u16* __restrict__ Qb, u16* __restrict__ Kb,
                             const float* __restrict__ cosT, const float* __restrict__ sinT) {
  int id = blockIdx.x * 256 + threadIdx.x;  // 163840*64
  int i = id & 63;
  int row = id >> 6;
  u16* base = (row < 131072) ? (Qb + (long)row * 128) : (Kb + (long)(row - 131072) * 128);
  int s = row & (SEQ - 1);
  float c = cosT[s * 64 + i], sn = sinT[s * 64 + i];
  float x0 = bf2f(base[i]), x1 = bf2f(base[i + 64]);
  base[i] = f2bf(x0 * c - x1 * sn);
  base[i + 64] = f2bf(x1 * c + x0 * sn);
}

// ========== 256x256 8-phase bf16 GEMM (T2+T3+T4+T5): A(MxK) @ Bt(NxK)^T ==========
// LDS (dynamic 128 KiB): buf{0,1} x { A_kh0, A_kh1, B_kh0, B_kh1 }, each [256][32] bf16
// = 16 KiB, XOR-swizzled slot s_stored = s ^ (row&3) (pre-swizzled global source,
// linear global_load_lds dest, swizzled ds_read).  8 waves (2M x 4N), per-wave 128x64.
// Per K-tile: 4 phases x 16 MFMA; counted vmcnt(4) once per K-tile (T4), never 0
// until the last two iterations.
__device__ __forceinline__ void stg(char* smem, int base, const u16* XG, long off,
                                    int K, int tid, int r0, int scol) {
  gll16((u16*)(smem + base + tid * 16), XG + (long)r0 * K + off + scol);
  gll16((u16*)(smem + base + 8192 + tid * 16), XG + (long)(r0 + 128) * K + off + scol);
}

#define GPHASE(MH, KH, READB, STG_STMT, WAIT_STMT)                                  \
  {                                                                                 \
    const char* Ab_ = smem + cbuf + (KH) * 16384;                                   \
    const char* Bb_ = smem + cbuf + 32768 + (KH) * 16384;                           \
    s16x8 Ar_[4];                                                                   \
    _Pragma("unroll")                                                               \
    for (int m_ = 0; m_ < 4; ++m_)                                                  \
      Ar_[m_] = *(const s16x8*)(Ab_ + aoff + ((MH) * 4 + m_) * 1024);               \
    if (READB) {                                                                    \
      _Pragma("unroll")                                                             \
      for (int n_ = 0; n_ < 4; ++n_)                                                \
        Br[n_] = *(const s16x8*)(Bb_ + boff + n_ * 1024);                           \
    }                                                                               \
    STG_STMT;                                                                       \
    __builtin_amdgcn_s_barrier();                                                   \
    asm volatile("s_waitcnt lgkmcnt(0)" ::: "memory");                              \
    __builtin_amdgcn_sched_barrier(0);                                              \
    __builtin_amdgcn_s_setprio(1);                                                  \
    _Pragma("unroll")                                                               \
    for (int m_ = 0; m_ < 4; ++m_) {                                                \
      _Pragma("unroll")                                                             \
      for (int n_ = 0; n_ < 4; ++n_)                                                \
        acc[(MH) * 4 + m_][n_] = __builtin_amdgcn_mfma_f32_16x16x32_bf16(           \
            Ar_[m_], Br[n_], acc[(MH) * 4 + m_][n_], 0, 0, 0);                      \
    }                                                                               \
    __builtin_amdgcn_s_setprio(0);                                                  \
    WAIT_STMT;                                                                      \
    __builtin_amdgcn_s_barrier();                                                   \
  }

template <int MODE>
__global__ __launch_bounds__(512, 1) void k_gemm256(
    const u16* __restrict__ A, const u16* __restrict__ Bt,
    float* __restrict__ Cf, const float* __restrict__ bias,
    u16* __restrict__ Qb, u16* __restrict__ Kb, u16* __restrict__ Vb,
    int K, int nbn) {
  extern __shared__ char smem[];
  int bid = blockIdx.x;
  int cpx = (int)gridDim.x >> 3;               // grid % 8 == 0 by construction
  int swz = (bid & 7) * cpx + (bid >> 3);      // XCD-contiguous logical ids
  int bm = swz / nbn, bn = swz - bm * nbn;
  int tid = threadIdx.x;
  int lane = tid & 63, wave = tid >> 6;
  int lo = lane & 15, hi = lane >> 4;
  int wm = wave >> 2, wn = wave & 3;           // 2 x 4 waves
  const u16* Ag = A + (long)bm * 256 * K;
  const u16* Bg = Bt + (long)bn * 256 * K;
  f32x4 zero4 = {0.f, 0.f, 0.f, 0.f};
  f32x4 acc[8][4];
#pragma unroll
  for (int m = 0; m < 8; ++m)
#pragma unroll
    for (int n = 0; n < 4; ++n) acc[m][n] = zero4;

  // ds_read fragment offsets (bytes within a [256][32] kh-array), swizzled
  int aoff = (wm * 128 + lo) * 64 + ((hi ^ (lo & 3)) << 4);
  int boff = (wn * 64 + lo) * 64 + ((hi ^ (lo & 3)) << 4);
  // staging per-thread constants
  int r0 = tid >> 2;
  int scol = (((tid & 3) ^ (r0 & 3)) << 3);

  int nt = K >> 6;  // K-tiles (64 for K=4096)
  // prologue: tile0 (all 4 half-tiles) -> buf0; tile1 kh0 -> buf1
  stg(smem, 0,             Ag, 0,  K, tid, r0, scol);
  stg(smem, 32768,         Bg, 0,  K, tid, r0, scol);
  stg(smem, 16384,         Ag, 32, K, tid, r0, scol);
  stg(smem, 49152,         Bg, 32, K, tid, r0, scol);
  stg(smem, 65536,         Ag, 64, K, tid, r0, scol);
  stg(smem, 65536 + 32768, Bg, 64, K, tid, r0, scol);
  asm volatile("s_waitcnt vmcnt(4)" ::: "memory");
  __builtin_amdgcn_s_barrier();

  s16x8 Br[4];
  for (int t = 0; t < nt; ++t) {
    int cbuf = (t & 1) << 16;
    int obuf = cbuf ^ 65536;
    long k1 = (long)(t + 1) * 64;
    long k2 = (long)(t + 2) * 64;
    bool s1ok = (t + 1) < nt, s2ok = (t + 2) < nt;
    GPHASE(0, 0, true,
           { if (s1ok) stg(smem, obuf + 16384, Ag, k1 + 32, K, tid, r0, scol); }, {})
    GPHASE(1, 0, false,
           { if (s1ok) stg(smem, obuf + 49152, Bg, k1 + 32, K, tid, r0, scol); }, {})
    GPHASE(0, 1, true,
           { if (s2ok) stg(smem, cbuf, Ag, k2, K, tid, r0, scol); }, {})
    GPHASE(1, 1, false,
           { if (s2ok) stg(smem, cbuf + 32768, Bg, k2, K, tid, r0, scol); },
           {
             if (s2ok)      asm volatile("s_waitcnt vmcnt(4)" ::: "memory");
             else if (s1ok) asm volatile("s_waitcnt vmcnt(0)" ::: "memory");
           })
  }

#pragma unroll
  for (int mr = 0; mr < 8; ++mr) {
#pragma unroll
    for (int n = 0; n < 4; ++n) {
      int colg = bn * 256 + wn * 64 + n * 16 + lo;
#pragma unroll
      for (int r = 0; r < 4; ++r) {
        int rowg = bm * 256 + wm * 128 + mr * 16 + hi * 4 + r;
        float v = acc[mr][n][r];
        if (MODE == 1) {
          Cf[(long)rowg * 4096 + colg] = v + bias[colg];
        } else {
          int bb = rowg >> 11, s = rowg & 2047;
          u16 u = f2bf(v);
          int d = colg & 127;
          if (colg < 4096) {
            int hh = colg >> 7;
            Qb[(((long)bb * NH + hh) * SEQ + s) * 128 + d] = u;
          } else if (colg < 5120) {
            int hh = (colg - 4096) >> 7;
            Kb[(((long)bb * NKV + hh) * SEQ + s) * 128 + d] = u;
          } else {
            int hh = (colg - 5120) >> 7;
            Vb[(((long)bb * NKV + hh) * SEQ + s) * 128 + d] = u;
          }
        }
      }
    }
  }
}

// ------- K/V^T staging: global->reg (issue early), reg->swizzled LDS (write late) -------
__device__ __forceinline__ void stage_load(u32x4* kr_, u32x4* vr_,
    const u16* __restrict__ Kg, const u16* __restrict__ Vg, int kt, int tid) {
#pragma unroll
  for (int i = 0; i < 4; ++i) {
    int idx = i * 256 + tid;
    int kr = idx >> 4, kc = idx & 15;
    kr_[i] = *(const u32x4*)&Kg[(long)(kt + kr) * 128 + kc * 8];
    int vr = idx >> 3, vc = idx & 7;
    vr_[i] = *(const u32x4*)&Vg[(long)vr * SEQ + kt + vc * 8];
  }
}
__device__ __forceinline__ void stage_write(const u32x4* kr_, const u32x4* vr_,
    u16* Ks, u16* Vs, int tid) {
  char* KsB = (char*)Ks; char* VsB = (char*)Vs;
#pragma unroll
  for (int i = 0; i < 4; ++i) {
    int idx = i * 256 + tid;
    int kr = idx >> 4, kc = idx & 15;
    *(u32x4*)(KsB + ((kr * 256 + kc * 16) ^ ((kr & 7) << 4))) = kr_[i];
    int vr = idx >> 3, vc = idx & 7;
    *(u32x4*)(VsB + ((vr * 128 + vc * 16) ^ ((vr & 7) << 4))) = vr_[i];
  }
}

// ------- causal GQA flash attn: 4 waves x 32 q-rows, KVBLK=64, swapped-operand -------
__global__ __launch_bounds__(256, 2) void k_attn(
    const u16* __restrict__ Qb, const u16* __restrict__ Kb,
    const u16* __restrict__ Vt, u16* __restrict__ AO) {
  __shared__ u16 Ks0[64 * 128], Ks1[64 * 128], Vs0[128 * 64], Vs1[128 * 64];
  __shared__ u16 Ps[4][2][16][32];  // [wave][qs][q=lo][key_local], 8B-chunk swizzled
  int gid = blockIdx.x;                      // 1024 blocks
  int wid = (gid & 7) * 128 + (gid >> 3);    // XCD-contiguous work ids
  int g = wid >> 6, w = wid & 63;
  int b = g >> 3, kvh = g & 7;
  int h = kvh * 4 + (w >> 4);
  int qt = 15 - (w & 15);                    // long blocks first
  int qb0 = qt * 128;
  int tid = threadIdx.x, lane = tid & 63, wave = tid >> 6;
  int lo = lane & 15, hi = lane >> 4;
  int q0w = qb0 + wave * 32;

  const u16* Kg = Kb + (long)(b * NKV + kvh) * SEQ * 128;
  const u16* Vg = Vt + (long)(b * NKV + kvh) * 128 * SEQ;
  const u16* Qg = Qb + (long)(b * NH + h) * SEQ * 128;

  // Q hoisted: B-frag of swapped QK^T = Q[q=lo][d=ds*32+hi*8+j]
  s16x8 qf[2][4];
#pragma unroll
  for (int qs = 0; qs < 2; ++qs)
#pragma unroll
    for (int ds = 0; ds < 4; ++ds)
      qf[qs][ds] = *(const s16x8*)&Qg[(long)(q0w + qs * 16 + lo) * 128 + ds * 32 + hi * 8];

  f32x4 zero4 = {0.f, 0.f, 0.f, 0.f};
  f32x4 o[2][8];
#pragma unroll
  for (int qs = 0; qs < 2; ++qs)
#pragma unroll
    for (int dt = 0; dt < 8; ++dt) o[qs][dt] = zero4;
  float m_run[2] = {-1e30f, -1e30f};
  float l_run[2] = {0.f, 0.f};
  const float scale = 0.088388347648318447f;  // 1/sqrt(128)

  char* PsQ0 = (char*)&Ps[wave][0][0][0];
  char* PsQ1 = (char*)&Ps[wave][1][0][0];
  int pbase = lo << 6;  // row stride 64B in the bounce buffer

  u32x4 kreg[4], vreg[4];
  int ntiles = (qb0 >> 6) + 2;
  stage_load(kreg, vreg, Kg, Vg, 0, tid);
  stage_write(kreg, vreg, Ks0, Vs0, tid);
  __syncthreads();

  for (int t = 0; t < ntiles; ++t) {
    int kt = t << 6;
    u16* Ks = (t & 1) ? Ks1 : Ks0;
    u16* Vs = (t & 1) ? Vs1 : Vs0;
    bool more = (t + 1 < ntiles);
    if (more) stage_load(kreg, vreg, Kg, Vg, (t + 1) << 6, tid);  // issue early (T14)
    if (kt <= q0w + 31) {
      // ---- QK^T (swapped): lane holds S[q=lo][key=kt+a*16+hi*4+r]
      f32x4 sa[2][4];
#pragma unroll
      for (int qs = 0; qs < 2; ++qs)
#pragma unroll
        for (int a = 0; a < 4; ++a) sa[qs][a] = zero4;
#pragma unroll
      for (int ds = 0; ds < 4; ++ds) {
        s16x8 kf[4];
#pragma unroll
        for (int a = 0; a < 4; ++a)
          kf[a] = *(const s16x8*)&Ks[((a * 16 + lo) << 7) + (((ds * 4 + hi) ^ (lo & 7)) << 3)];
#pragma unroll
        for (int qs = 0; qs < 2; ++qs)
#pragma unroll
          for (int a = 0; a < 4; ++a)
            sa[qs][a] = __builtin_amdgcn_mfma_f32_16x16x32_bf16(kf[a], qf[qs][ds], sa[qs][a], 0, 0, 0);
      }
      bool pmask = (kt + 63) > q0w;
      u32 pp[2][4][2];
#pragma unroll
      for (int qs = 0; qs < 2; ++qs) {
        float pv[16];
        int qrow = q0w + qs * 16 + lo;
#pragma unroll
        for (int a = 0; a < 4; ++a)
#pragma unroll
          for (int r = 0; r < 4; ++r) {
            float s = sa[qs][a][r] * scale;
            if (pmask && (kt + a * 16 + hi * 4 + r) > qrow) s = -1e30f;
            pv[a * 4 + r] = s;
          }
        float mx = pv[0];
#pragma unroll
        for (int i = 1; i < 16; ++i) mx = fmaxf(mx, pv[i]);
        mx = fmaxf(mx, __shfl_xor(mx, 16));
        mx = fmaxf(mx, __shfl_xor(mx, 32));
        float mnew = fmaxf(m_run[qs], mx);
        if (!__all(mnew - m_run[qs] <= 8.0f)) {  // defer-max (T13)
          float corr = __expf(m_run[qs] - mnew);
          m_run[qs] = mnew;
          l_run[qs] *= corr;
#pragma unroll
          for (int dt = 0; dt < 8; ++dt)
#pragma unroll
            for (int r = 0; r < 4; ++r) o[qs][dt][r] *= corr;
        }
        float sum = 0.f;
#pragma unroll
        for (int i = 0; i < 16; ++i) { pv[i] = __expf(pv[i] - m_run[qs]); sum += pv[i]; }
        sum += __shfl_xor(sum, 16);
        sum += __shfl_xor(sum, 32);
        l_run[qs] += sum;
#pragma unroll
        for (int a = 0; a < 4; ++a) {
          pp[qs][a][0] = pack2(pv[a * 4 + 0], pv[a * 4 + 1]);
          pp[qs][a][1] = pack2(pv[a * 4 + 2], pv[a * 4 + 3]);
        }
      }
      // ---- PV (swapped): O^T = mfma(V^T, P^T); P^T B-frag via LDS bounce per kb-half
#pragma unroll
      for (int kb = 0; kb < 2; ++kb) {
#pragma unroll
        for (int qs = 0; qs < 2; ++qs) {
          char* Pw = qs ? PsQ1 : PsQ0;
#pragma unroll
          for (int al = 0; al < 2; ++al) {
            uint2 wv; wv.x = pp[qs][kb * 2 + al][0]; wv.y = pp[qs][kb * 2 + al][1];
            *(uint2*)(Pw + pbase + (((al * 4 + hi) ^ (lo & 7)) << 3)) = wv;
          }
        }
        asm volatile("s_waitcnt lgkmcnt(0)" ::: "memory");
        __builtin_amdgcn_sched_barrier(0);
        union { uint2 u2[2]; s16x8 v; } bu0, bu1;
        bu0.u2[0] = *(uint2*)(PsQ0 + pbase + (((hi * 2 + 0) ^ (lo & 7)) << 3));
        bu0.u2[1] = *(uint2*)(PsQ0 + pbase + (((hi * 2 + 1) ^ (lo & 7)) << 3));
        bu1.u2[0] = *(uint2*)(PsQ1 + pbase + (((hi * 2 + 0) ^ (lo & 7)) << 3));
        bu1.u2[1] = *(uint2*)(PsQ1 + pbase + (((hi * 2 + 1) ^ (lo & 7)) << 3));
#pragma unroll
        for (int dt = 0; dt < 8; ++dt) {
          s16x8 vf = *(const s16x8*)((char*)Vs +
              (((dt * 16 + lo) * 128 + (kb * 4 + hi) * 16) ^ ((lo & 7) << 4)));
          o[0][dt] = __builtin_amdgcn_mfma_f32_16x16x32_bf16(vf, bu0.v, o[0][dt], 0, 0, 0);
          o[1][dt] = __builtin_amdgcn_mfma_f32_16x16x32_bf16(vf, bu1.v, o[1][dt], 0, 0, 0);
        }
      }
    }
    if (more) stage_write(kreg, vreg, (t & 1) ? Ks0 : Ks1, (t & 1) ? Vs0 : Vs1, tid);
    __syncthreads();
  }

  // epilogue: lane holds O[q=lo][d=dt*16+hi*4+r]
#pragma unroll
  for (int qs = 0; qs < 2; ++qs) {
    float inv = 1.0f / l_run[qs];
    long base = ((long)(b * SEQ + q0w + qs * 16 + lo)) * 4096 + h * 128;
#pragma unroll
    for (int dt = 0; dt < 8; ++dt) {
      uint2 wv;
      wv.x = pack2(o[qs][dt][0] * inv, o[qs][dt][1] * inv);
      wv.y = pack2(o[qs][dt][2] * inv, o[qs][dt][3] * inv);
      *(uint2*)&AO[base + dt * 16 + hi * 4] = wv;
    }
  }
}

extern "C" void kernel_launch(void* const* d_in, const int* in_sizes, int n_in,
                              void* d_out, int out_size, void* d_ws, size_t ws_size,
                              hipStream_t stream) {
  const float* x  = (const float*)d_in[0];
  const float* Wq = (const float*)d_in[1];
  const float* Wk = (const float*)d_in[2];
  const float* Wv = (const float*)d_in[3];
  const float* Wo = (const float*)d_in[4];
  const float* bo = (const float*)d_in[5];
  float* out = (float*)d_out;

  char* ws = (char*)d_ws;
  u16* xb     = (u16*)(ws);               // 32 MiB; reused as AO after gemm1
  u16* Wt     = (u16*)(ws + 33554432);    // 48 MiB (QKV cat); first 32 MiB reused for Wo^T
  u16* Vtb    = (u16*)(ws + 67108864);    // 8 MiB (V^T per head, d x S) - tail of Wt region
  u16* Qb     = (u16*)(ws + 83886080);    // 32 MiB
  u16* Kb     = (u16*)(ws + 117440512);   // 8 MiB
  u16* Vb     = (u16*)(ws + 125829120);   // 8 MiB
  float* cosT = (float*)(ws + 134217728); // 512 KiB
  float* sinT = (float*)(ws + 134742016); // 512 KiB
  if (ws_size < 135266304) return;        // need 129 MiB scratch
  u16* AO  = xb;
  u16* Wto = Wt;

  (void)hipFuncSetAttribute((const void*)k_gemm256<0>,
                            hipFuncAttributeMaxDynamicSharedMemorySize, 131072);
  (void)hipFuncSetAttribute((const void*)k_gemm256<1>,
                            hipFuncAttributeMaxDynamicSharedMemorySize, 131072);

  k_conv_bf16<<<16384, 256, 0, stream>>>(x, xb);
  k_transpose_bf16<<<dim3(64, 64), 256, 0, stream>>>(Wq, Wt, 4096, 4096);
  k_transpose_bf16<<<dim3(16, 64), 256, 0, stream>>>(Wk, Wt + (long)4096 * 4096, 4096, 1024);
  k_transpose_bf16<<<dim3(16, 64), 256, 0, stream>>>(Wv, Wt + (long)5120 * 4096, 4096, 1024);
  k_rope_table<<<512, 256, 0, stream>>>(cosT, sinT);
  k_gemm256<0><<<384, 512, 131072, stream>>>(xb, Wt, nullptr, nullptr, Qb, Kb, Vb, 4096, 24);
  k_vt<<<dim3(32, 16), 256, 0, stream>>>(Vb, Vtb);
  k_rope_apply<<<40960, 256, 0, stream>>>(Qb, Kb, cosT, sinT);
  k_transpose_bf16<<<dim3(64, 64), 256, 0, stream>>>(Wo, Wto, 4096, 4096);
  k_attn<<<1024, 256, 0, stream>>>(Qb, Kb, Vtb, AO);
  k_gemm256<1><<<256, 512, 131072, stream>>>(AO, Wto, out, bo, nullptr, nullptr, nullptr, 4096, 16);
}